// Round 7
// baseline (299.777 us; speedup 1.0000x reference)
//
#include <hip/hip_runtime.h>

#define NFFT  2048
#define KF    1025
#define MROWS 2050
#define TT    513
#define HOPS  512
#define LSIG  262144
#define PADL  1024
#define XPADN 264192              // LSIG + 2*PADL
#define XDN   66048               // XPADN / 4 (deinterleaved plane length)
#define IMOFF (16 * MROWS * TT)
#define NBC   32
#define APL   262144              // A elements per r-plane (512*512)

typedef __attribute__((ext_vector_type(8))) short bf16x8;
typedef __attribute__((ext_vector_type(4))) short bf16x4;
typedef __attribute__((ext_vector_type(4))) float f32x4;

__device__ __forceinline__ short f2bf(float f) {
    union { float f; unsigned u; } v; v.f = f;
    unsigned r = v.u + 0x7fffu + ((v.u >> 16) & 1u);
    return (short)(r >> 16);
}

typedef __attribute__((address_space(1))) void gas_void;
typedef __attribute__((address_space(3))) void las_void;

__device__ __forceinline__ void gload_lds16(const short* g, short* l) {
    __builtin_amdgcn_global_load_lds((gas_void*)(void*)const_cast<short*>(g),
                                     (las_void*)(void*)l, 16, 0, 0);
}

// ---- prep: reflect-padded x -> bf16 xpad[32][264192] AND deinterleaved xd[4][32][66048]
__global__ __launch_bounds__(256)
void prep_x(const float* __restrict__ x, short* __restrict__ xpad,
            short* __restrict__ xd) {
    const int bc = blockIdx.y;
    const int j4 = (blockIdx.x * 256 + threadIdx.x) * 4;   // 258*256*4 = 264192 exact
    const float* xb = x + (size_t)bc * LSIG;
    float4 v;
    if (j4 >= PADL && j4 + 4 <= PADL + LSIG) {
        v = *(const float4*)(xb + (j4 - PADL));
    } else {
        float t[4];
#pragma unroll
        for (int e = 0; e < 4; e++) {
            int s = j4 + e - PADL;
            if (s < 0) s = -s;
            if (s >= LSIG) s = 2 * LSIG - 2 - s;
            t[e] = xb[s];
        }
        v = make_float4(t[0], t[1], t[2], t[3]);
    }
    bf16x4 b = { f2bf(v.x), f2bf(v.y), f2bf(v.z), f2bf(v.w) };
    *(bf16x4*)(xpad + (size_t)bc * XPADN + j4) = b;
    const int j = j4 >> 2;                                 // n = 4j + r
#pragma unroll
    for (int r = 0; r < 4; r++)
        xd[((size_t)r * NBC + bc) * XDN + j] = b[r];
}

// ---- prep: twiddle-baked radix-4 basis.
// A'[r][row=2kap+reim][m] = (reim ? wi : wr)[kap][4m+r]  (pure gather, no trig)
__global__ __launch_bounds__(256)
void prep_basis2(const float* __restrict__ wr, const float* __restrict__ wi,
                 short* __restrict__ A) {
    const int r   = blockIdx.y;
    const int row = blockIdx.x;               // 0..511, kap = row>>1
    const float* w = ((row & 1) ? wi : wr) + (size_t)(row >> 1) * NFFT + r;
    short* dst = A + ((size_t)r * 512 + row) * 512;
    for (int m = threadIdx.x; m < 512; m += 256)
        dst[m] = f2bf(w[4 * m]);
}

// ---- fused radix-4 GEMM, plane-per-wave, barrier-free main loop, K-step 32.
// Block: 64 basis rows (32 kaps) x 64 t; 4 waves, wave r owns plane r (64x64 tile,
// acc 4x4 = 64 VGPR). Private 16 KB dbuf strip per wave (A 4K + B 4K per buf);
// per step: issue 8 gload_lds for next buf, s_waitcnt vmcnt(8), 8 ds_read + 16 MFMA,
// then sched_barrier(0): forbids the NEXT step's gloads (which overwrite the buffer
// just read) from being scheduler-hoisted above this step's ds_reads (R6 race fix).
// No __syncthreads in K loop. Butterfly via LDS exchange after. 68 KB dyn LDS ->
// 2 blocks/CU. Grid flattened: phys bid keeps the 8 y-variants of a (bc,z) group
// on one XCD (phys % 8 == group % 8) for B-tile L2 reuse.
__global__ __launch_bounds__(256, 2)
void stft_gemm_f(const short* __restrict__ Ab, const short* __restrict__ xd,
                 float* __restrict__ out) {
    extern __shared__ short lds[];             // 69632 B

    const int bid = blockIdx.x;                // 0..2303
    const int g   = (bid & 7) + 8 * (bid >> 6);    // group = bc + 32*z, 0..287
    const int y   = (bid >> 3) & 7;
    const int bcg = g & 31;
    const int z   = g >> 5;                    // 0..8
    const int mBase = y * 64;
    const int t0    = z * 64;

    const int tid  = threadIdx.x;
    const int lane = tid & 63;
    const int r    = tid >> 6;                 // wave id == r-plane

    const int l16  = lane & 15;
    const int quad = lane >> 4;
    const int lrow = lane >> 2;                // 0..15 (row within 16-row group)
    const int csrc = (lane & 3) ^ (lrow & 3);  // staged source chunk (involution)

    short* strip = lds + r * 8192;             // 16 KB per wave (shorts)
    // strip layout (shorts): buf0 A @0 [64][32], buf0 B @2048, buf1 @4096/@6144

    // global sources
    const short* aRow = Ab + (size_t)r * APL + (size_t)(mBase + lrow) * 512 + csrc * 8;
    const short* bPlane = xd + ((size_t)r * NBC + bcg) * XDN + csrc * 8;
    const short* bRow[4];
#pragma unroll
    for (int i = 0; i < 4; i++) {
        int bt = t0 + 16 * i + lrow; if (bt > 512) bt = 512;   // in-plane clamp
        bRow[i] = bPlane + (size_t)bt * 128;
    }

    f32x4 acc[4][4];
#pragma unroll
    for (int i = 0; i < 4; i++)
#pragma unroll
        for (int j = 0; j < 4; j++)
            acc[i][j] = (f32x4){0.f, 0.f, 0.f, 0.f};

    const int lsw = (l16 & 3);                 // read-side XOR key

    // prologue: stage step 0 into buf0 (8 loads)
#pragma unroll
    for (int i = 0; i < 4; i++) {
        gload_lds16(aRow + i * 8192, strip + i * 512);
        gload_lds16(bRow[i],         strip + 2048 + i * 512);
    }

    for (int kt = 0; kt < 512; kt += 32) {
        const int cur = (kt >> 5) & 1;
        if (kt < 480) {
            short* d = strip + ((cur ^ 1) << 12);
            const int ko = kt + 32;
#pragma unroll
            for (int i = 0; i < 4; i++) {
                gload_lds16(aRow + i * 8192 + ko, d + i * 512);
                gload_lds16(bRow[i] + ko,         d + 2048 + i * 512);
            }
            asm volatile("s_waitcnt vmcnt(8)" ::: "memory");
        } else {
            asm volatile("s_waitcnt vmcnt(0)" ::: "memory");
        }
        __builtin_amdgcn_sched_barrier(0);
        const short* Ac = strip + (cur << 12);
        const short* Bc = Ac + 2048;
        bf16x8 af[4], bfr[4];
#pragma unroll
        for (int i = 0; i < 4; i++)
            af[i] = *(const bf16x8*)(Ac + (i * 16 + l16) * 32 + ((quad ^ lsw) * 8));
#pragma unroll
        for (int j = 0; j < 4; j++)
            bfr[j] = *(const bf16x8*)(Bc + (j * 16 + l16) * 32 + ((quad ^ lsw) * 8));
#pragma unroll
        for (int i = 0; i < 4; i++)
#pragma unroll
            for (int j = 0; j < 4; j++)
                acc[i][j] = __builtin_amdgcn_mfma_f32_16x16x32_bf16(
                    af[i], bfr[j], acc[i][j], 0, 0, 0);
        // R6 race fix: pin this step's reads/MFMAs before next step's stage issues.
        __builtin_amdgcn_sched_barrier(0);
    }

    // ---- butterfly via LDS exchange ----
    __syncthreads();
    float* sf = (float*)lds;
    float* Sr = sf + r * (64 * 66);            // stride 66: 2-way banks (free)
#pragma unroll
    for (int i = 0; i < 4; i++)
#pragma unroll
        for (int j = 0; j < 4; j++)
#pragma unroll
            for (int rr = 0; rr < 4; rr++)
                Sr[(i * 16 + quad * 4 + rr) * 66 + j * 16 + l16] = acc[i][j][rr];
    __syncthreads();

    float* oRe = out + (size_t)bcg * KF * TT;
    float* oIm = out + (size_t)IMOFF + (size_t)bcg * KF * TT;
    const int tg = t0 + lane;
    if (tg < TT) {
#pragma unroll
        for (int kl = 0; kl < 8; kl++) {
            const int kap = r * 8 + kl;                 // local kap 0..31
            const int kg  = (mBase >> 1) + kap;         // global kap 0..255
            float u0 = sf[0 * 4224 + (2 * kap) * 66 + lane];
            float v0 = sf[0 * 4224 + (2 * kap + 1) * 66 + lane];
            float u1 = sf[1 * 4224 + (2 * kap) * 66 + lane];
            float v1 = sf[1 * 4224 + (2 * kap + 1) * 66 + lane];
            float u2 = sf[2 * 4224 + (2 * kap) * 66 + lane];
            float v2 = sf[2 * 4224 + (2 * kap + 1) * 66 + lane];
            float u3 = sf[3 * 4224 + (2 * kap) * 66 + lane];
            float v3 = sf[3 * 4224 + (2 * kap + 1) * 66 + lane];
            const float Eu = u0 + u2, Epu = u0 - u2;
            const float Ou = u1 + u3, Opu = u1 - u3;
            const float Ev = v0 + v2, Epv = v0 - v2;
            const float Ov = v1 + v3, Opv = v1 - v3;
            const size_t rA = (size_t)kg * TT + tg;
            const size_t rB = (size_t)(kg + 512) * TT + tg;
            const size_t rC = (size_t)(512 - kg) * TT + tg;
            const size_t rD = (size_t)(1024 - kg) * TT + tg;
            oRe[rA] = Eu + Ou;    oIm[rA] = Ev + Ov;
            oRe[rB] = Epu + Opv;  oIm[rB] = Epv - Opu;
            oRe[rC] = Epu - Opv;  oIm[rC] = -(Epv + Opu);
            oRe[rD] = Eu - Ou;    oIm[rD] = -(Ev - Ov);
        }
    }
}

// ---- tail: k in {256,768} re/im, t in [0,513)  (t=512 via clamped frame row)
__global__ __launch_bounds__(256)
void stft_tail(const float* __restrict__ wr, const float* __restrict__ wi,
               const short* __restrict__ xpad, float* __restrict__ out) {
    const int tb  = blockIdx.x;          // 0..8
    const int bc  = blockIdx.y;          // 0..31
    const int tid = threadIdx.x;
    const int lane = tid & 63;
    const int wid  = tid >> 6;
    const int l16  = lane & 15;
    const int quad = lane >> 4;

    const int t0 = (tb * 4 + wid) * 16;  // 0..560
    const int ls = l16 & 3;
    const int k  = 256 + (ls & 1) * 512;
    const float* bp = ((ls & 2) ? wi : wr) + (size_t)k * NFFT + quad * 8;
    const int tr = min(t0 + l16, 512);
    const short* ap = xpad + (size_t)bc * XPADN + (size_t)tr * HOPS + quad * 8;
    f32x4 acc0 = {0.f, 0.f, 0.f, 0.f}, acc1 = {0.f, 0.f, 0.f, 0.f};
    for (int kt = 0; kt < NFFT; kt += 64) {
        bf16x8 a0 = *(const bf16x8*)(ap + kt);
        bf16x8 a1 = *(const bf16x8*)(ap + kt + 32);
        float4 f0 = *(const float4*)(bp + kt), f1 = *(const float4*)(bp + kt + 4);
        float4 g0 = *(const float4*)(bp + kt + 32), g1 = *(const float4*)(bp + kt + 36);
        bf16x8 b0 = { f2bf(f0.x), f2bf(f0.y), f2bf(f0.z), f2bf(f0.w),
                      f2bf(f1.x), f2bf(f1.y), f2bf(f1.z), f2bf(f1.w) };
        bf16x8 b1 = { f2bf(g0.x), f2bf(g0.y), f2bf(g0.z), f2bf(g0.w),
                      f2bf(g1.x), f2bf(g1.y), f2bf(g1.z), f2bf(g1.w) };
        acc0 = __builtin_amdgcn_mfma_f32_16x16x32_bf16(a0, b0, acc0, 0, 0, 0);
        acc1 = __builtin_amdgcn_mfma_f32_16x16x32_bf16(a1, b1, acc1, 0, 0, 0);
    }
    if (l16 < 4) {
        size_t base = ((ls & 2) ? (size_t)IMOFF : 0) + (size_t)(bc * KF + k) * TT;
#pragma unroll
        for (int rr = 0; rr < 4; rr++) {
            int t = t0 + quad * 4 + rr;
            if (t < TT) out[base + t] = acc0[rr] + acc1[rr];
        }
    }
}

extern "C" void kernel_launch(void* const* d_in, const int* in_sizes, int n_in,
                              void* d_out, int out_size, void* d_ws, size_t ws_size,
                              hipStream_t stream) {
    const float* x  = (const float*)d_in[0];
    const float* wr = (const float*)d_in[1];
    const float* wi = (const float*)d_in[2];
    float* out = (float*)d_out;

    char* ws = (char*)d_ws;
    short* xpad = (short*)ws;                                  // 16,908,288 B
    short* xd   = (short*)(ws + 16908288);                     // 16,908,288 B
    short* Ab   = (short*)(ws + 33816576);                     //  2,097,152 B

    static bool cfgDone = false;
    if (!cfgDone) {
        (void)hipFuncSetAttribute((const void*)stft_gemm_f,
                                  hipFuncAttributeMaxDynamicSharedMemorySize,
                                  69632);
        cfgDone = true;
    }

    prep_x<<<dim3(258, NBC), 256, 0, stream>>>(x, xpad, xd);
    prep_basis2<<<dim3(512, 4), 256, 0, stream>>>(wr, wi, Ab);
    stft_gemm_f<<<dim3(2304), 256, 69632, stream>>>(Ab, xd, out);
    stft_tail<<<dim3(9, NBC), 256, 0, stream>>>(wr, wi, xpad, out);
}

// Round 8
// 296.826 us; speedup vs baseline: 1.0099x; 1.0099x over previous
//
#include <hip/hip_runtime.h>

#define NFFT  2048
#define KF    1025
#define MROWS 2050
#define TT    513
#define HOPS  512
#define LSIG  262144
#define PADL  1024
#define XPADN 264192              // LSIG + 2*PADL
#define XDN   66048               // XPADN / 4 (deinterleaved plane length)
#define IMOFF (16 * MROWS * TT)
#define NBC   32
#define APL   262144              // A elements per r-plane (512*512)

typedef __attribute__((ext_vector_type(8))) short bf16x8;
typedef __attribute__((ext_vector_type(4))) short bf16x4;
typedef __attribute__((ext_vector_type(4))) float f32x4;

__device__ __forceinline__ short f2bf(float f) {
    union { float f; unsigned u; } v; v.f = f;
    unsigned r = v.u + 0x7fffu + ((v.u >> 16) & 1u);
    return (short)(r >> 16);
}

typedef __attribute__((address_space(1))) void gas_void;
typedef __attribute__((address_space(3))) void las_void;

__device__ __forceinline__ void gload_lds16(const short* g, short* l) {
    __builtin_amdgcn_global_load_lds((gas_void*)(void*)const_cast<short*>(g),
                                     (las_void*)(void*)l, 16, 0, 0);
}

// ---- prep: reflect-padded x -> bf16 xpad[32][264192] AND deinterleaved xd[4][32][66048]
__global__ __launch_bounds__(256)
void prep_x(const float* __restrict__ x, short* __restrict__ xpad,
            short* __restrict__ xd) {
    const int bc = blockIdx.y;
    const int j4 = (blockIdx.x * 256 + threadIdx.x) * 4;   // 258*256*4 = 264192 exact
    const float* xb = x + (size_t)bc * LSIG;
    float4 v;
    if (j4 >= PADL && j4 + 4 <= PADL + LSIG) {
        v = *(const float4*)(xb + (j4 - PADL));
    } else {
        float t[4];
#pragma unroll
        for (int e = 0; e < 4; e++) {
            int s = j4 + e - PADL;
            if (s < 0) s = -s;
            if (s >= LSIG) s = 2 * LSIG - 2 - s;
            t[e] = xb[s];
        }
        v = make_float4(t[0], t[1], t[2], t[3]);
    }
    bf16x4 b = { f2bf(v.x), f2bf(v.y), f2bf(v.z), f2bf(v.w) };
    *(bf16x4*)(xpad + (size_t)bc * XPADN + j4) = b;
    const int j = j4 >> 2;                                 // n = 4j + r
#pragma unroll
    for (int r = 0; r < 4; r++)
        xd[((size_t)r * NBC + bc) * XDN + j] = b[r];
}

// ---- prep: twiddle-baked radix-4 basis.
// A'[r][row=2kap+reim][m] = (reim ? wi : wr)[kap][4m+r]  (pure gather, no trig)
__global__ __launch_bounds__(256)
void prep_basis2(const float* __restrict__ wr, const float* __restrict__ wi,
                 short* __restrict__ A) {
    const int r   = blockIdx.y;
    const int row = blockIdx.x;               // 0..511, kap = row>>1
    const float* w = ((row & 1) ? wi : wr) + (size_t)(row >> 1) * NFFT + r;
    short* dst = A + ((size_t)r * 512 + row) * 512;
    for (int m = threadIdx.x; m < 512; m += 256)
        dst[m] = f2bf(w[4 * m]);
}

// ---- fused radix-4 GEMM, plane-per-wave, barrier-free main loop, K-step 32.
// Block: 64 basis rows (32 kaps) x 64 t; 4 waves, wave r owns plane r (64x64 tile,
// acc 4x4 = 64 VGPR). Private 16 KB dbuf strip per wave (A 4K + B 4K per buf);
// per step: issue 8 gload_lds for next buf, s_waitcnt vmcnt(8), 8 ds_read + 16 MFMA,
// then sched_barrier(0) (R6 fix: next step's gloads can't hoist above the reads).
// Bank swizzle: 64B rows -> bank base 16*(row&1); chunk key must be (row>>1)&3 so
// each quarter-wave hits every bank exactly twice (2-way = free). R7's row&3 key
// was parity-correlated -> 4-way conflict; fixed here on BOTH stage and read side.
// No __syncthreads in K loop. Butterfly via LDS exchange after. 68 KB dyn LDS ->
// 2 blocks/CU. Grid flattened: phys bid keeps the 8 y-variants of a (bc,z) group
// on one XCD (phys % 8 == group % 8) for B-tile L2 reuse.
__global__ __launch_bounds__(256, 2)
void stft_gemm_f(const short* __restrict__ Ab, const short* __restrict__ xd,
                 float* __restrict__ out) {
    extern __shared__ short lds[];             // 69632 B

    const int bid = blockIdx.x;                // 0..2303
    const int g   = (bid & 7) + 8 * (bid >> 6);    // group = bc + 32*z, 0..287
    const int y   = (bid >> 3) & 7;
    const int bcg = g & 31;
    const int z   = g >> 5;                    // 0..8
    const int mBase = y * 64;
    const int t0    = z * 64;

    const int tid  = threadIdx.x;
    const int lane = tid & 63;
    const int r    = tid >> 6;                 // wave id == r-plane

    const int l16  = lane & 15;
    const int quad = lane >> 4;
    const int lrow = lane >> 2;                // 0..15 (row within 16-row group)
    const int csrc = (lane & 3) ^ ((lrow >> 1) & 3);  // involution key (row>>1)&3

    short* strip = lds + r * 8192;             // 16 KB per wave (shorts)
    // strip layout (shorts): buf0 A @0 [64][32], buf0 B @2048, buf1 @4096/@6144

    // global sources
    const short* aRow = Ab + (size_t)r * APL + (size_t)(mBase + lrow) * 512 + csrc * 8;
    const short* bPlane = xd + ((size_t)r * NBC + bcg) * XDN + csrc * 8;
    const short* bRow[4];
#pragma unroll
    for (int i = 0; i < 4; i++) {
        int bt = t0 + 16 * i + lrow; if (bt > 512) bt = 512;   // in-plane clamp
        bRow[i] = bPlane + (size_t)bt * 128;
    }

    f32x4 acc[4][4];
#pragma unroll
    for (int i = 0; i < 4; i++)
#pragma unroll
        for (int j = 0; j < 4; j++)
            acc[i][j] = (f32x4){0.f, 0.f, 0.f, 0.f};

    const int lsw = (l16 >> 1) & 3;            // read-side XOR key = (row>>1)&3

    // prologue: stage step 0 into buf0 (8 loads)
#pragma unroll
    for (int i = 0; i < 4; i++) {
        gload_lds16(aRow + i * 8192, strip + i * 512);
        gload_lds16(bRow[i],         strip + 2048 + i * 512);
    }

    for (int kt = 0; kt < 512; kt += 32) {
        const int cur = (kt >> 5) & 1;
        if (kt < 480) {
            short* d = strip + ((cur ^ 1) << 12);
            const int ko = kt + 32;
#pragma unroll
            for (int i = 0; i < 4; i++) {
                gload_lds16(aRow + i * 8192 + ko, d + i * 512);
                gload_lds16(bRow[i] + ko,         d + 2048 + i * 512);
            }
            asm volatile("s_waitcnt vmcnt(8)" ::: "memory");
        } else {
            asm volatile("s_waitcnt vmcnt(0)" ::: "memory");
        }
        __builtin_amdgcn_sched_barrier(0);
        const short* Ac = strip + (cur << 12);
        const short* Bc = Ac + 2048;
        bf16x8 af[4], bfr[4];
#pragma unroll
        for (int i = 0; i < 4; i++)
            af[i] = *(const bf16x8*)(Ac + (i * 16 + l16) * 32 + ((quad ^ lsw) * 8));
#pragma unroll
        for (int j = 0; j < 4; j++)
            bfr[j] = *(const bf16x8*)(Bc + (j * 16 + l16) * 32 + ((quad ^ lsw) * 8));
#pragma unroll
        for (int i = 0; i < 4; i++)
#pragma unroll
            for (int j = 0; j < 4; j++)
                acc[i][j] = __builtin_amdgcn_mfma_f32_16x16x32_bf16(
                    af[i], bfr[j], acc[i][j], 0, 0, 0);
        // R6 race fix: pin this step's reads/MFMAs before next step's stage issues.
        __builtin_amdgcn_sched_barrier(0);
    }

    // ---- butterfly via LDS exchange ----
    __syncthreads();
    float* sf = (float*)lds;
    float* Sr = sf + r * (64 * 66);            // stride 66: 2-way banks (free)
#pragma unroll
    for (int i = 0; i < 4; i++)
#pragma unroll
        for (int j = 0; j < 4; j++)
#pragma unroll
            for (int rr = 0; rr < 4; rr++)
                Sr[(i * 16 + quad * 4 + rr) * 66 + j * 16 + l16] = acc[i][j][rr];
    __syncthreads();

    float* oRe = out + (size_t)bcg * KF * TT;
    float* oIm = out + (size_t)IMOFF + (size_t)bcg * KF * TT;
    const int tg = t0 + lane;
    if (tg < TT) {
#pragma unroll
        for (int kl = 0; kl < 8; kl++) {
            const int kap = r * 8 + kl;                 // local kap 0..31
            const int kg  = (mBase >> 1) + kap;         // global kap 0..255
            float u0 = sf[0 * 4224 + (2 * kap) * 66 + lane];
            float v0 = sf[0 * 4224 + (2 * kap + 1) * 66 + lane];
            float u1 = sf[1 * 4224 + (2 * kap) * 66 + lane];
            float v1 = sf[1 * 4224 + (2 * kap + 1) * 66 + lane];
            float u2 = sf[2 * 4224 + (2 * kap) * 66 + lane];
            float v2 = sf[2 * 4224 + (2 * kap + 1) * 66 + lane];
            float u3 = sf[3 * 4224 + (2 * kap) * 66 + lane];
            float v3 = sf[3 * 4224 + (2 * kap + 1) * 66 + lane];
            const float Eu = u0 + u2, Epu = u0 - u2;
            const float Ou = u1 + u3, Opu = u1 - u3;
            const float Ev = v0 + v2, Epv = v0 - v2;
            const float Ov = v1 + v3, Opv = v1 - v3;
            const size_t rA = (size_t)kg * TT + tg;
            const size_t rB = (size_t)(kg + 512) * TT + tg;
            const size_t rC = (size_t)(512 - kg) * TT + tg;
            const size_t rD = (size_t)(1024 - kg) * TT + tg;
            oRe[rA] = Eu + Ou;    oIm[rA] = Ev + Ov;
            oRe[rB] = Epu + Opv;  oIm[rB] = Epv - Opu;
            oRe[rC] = Epu - Opv;  oIm[rC] = -(Epv + Opu);
            oRe[rD] = Eu - Ou;    oIm[rD] = -(Ev - Ov);
        }
    }
}

// ---- tail: k in {256,768} re/im, t in [0,513)  (t=512 via clamped frame row)
__global__ __launch_bounds__(256)
void stft_tail(const float* __restrict__ wr, const float* __restrict__ wi,
               const short* __restrict__ xpad, float* __restrict__ out) {
    const int tb  = blockIdx.x;          // 0..8
    const int bc  = blockIdx.y;          // 0..31
    const int tid = threadIdx.x;
    const int lane = tid & 63;
    const int wid  = tid >> 6;
    const int l16  = lane & 15;
    const int quad = lane >> 4;

    const int t0 = (tb * 4 + wid) * 16;  // 0..560
    const int ls = l16 & 3;
    const int k  = 256 + (ls & 1) * 512;
    const float* bp = ((ls & 2) ? wi : wr) + (size_t)k * NFFT + quad * 8;
    const int tr = min(t0 + l16, 512);
    const short* ap = xpad + (size_t)bc * XPADN + (size_t)tr * HOPS + quad * 8;
    f32x4 acc0 = {0.f, 0.f, 0.f, 0.f}, acc1 = {0.f, 0.f, 0.f, 0.f};
    for (int kt = 0; kt < NFFT; kt += 64) {
        bf16x8 a0 = *(const bf16x8*)(ap + kt);
        bf16x8 a1 = *(const bf16x8*)(ap + kt + 32);
        float4 f0 = *(const float4*)(bp + kt), f1 = *(const float4*)(bp + kt + 4);
        float4 g0 = *(const float4*)(bp + kt + 32), g1 = *(const float4*)(bp + kt + 36);
        bf16x8 b0 = { f2bf(f0.x), f2bf(f0.y), f2bf(f0.z), f2bf(f0.w),
                      f2bf(f1.x), f2bf(f1.y), f2bf(f1.z), f2bf(f1.w) };
        bf16x8 b1 = { f2bf(g0.x), f2bf(g0.y), f2bf(g0.z), f2bf(g0.w),
                      f2bf(g1.x), f2bf(g1.y), f2bf(g1.z), f2bf(g1.w) };
        acc0 = __builtin_amdgcn_mfma_f32_16x16x32_bf16(a0, b0, acc0, 0, 0, 0);
        acc1 = __builtin_amdgcn_mfma_f32_16x16x32_bf16(a1, b1, acc1, 0, 0, 0);
    }
    if (l16 < 4) {
        size_t base = ((ls & 2) ? (size_t)IMOFF : 0) + (size_t)(bc * KF + k) * TT;
#pragma unroll
        for (int rr = 0; rr < 4; rr++) {
            int t = t0 + quad * 4 + rr;
            if (t < TT) out[base + t] = acc0[rr] + acc1[rr];
        }
    }
}

extern "C" void kernel_launch(void* const* d_in, const int* in_sizes, int n_in,
                              void* d_out, int out_size, void* d_ws, size_t ws_size,
                              hipStream_t stream) {
    const float* x  = (const float*)d_in[0];
    const float* wr = (const float*)d_in[1];
    const float* wi = (const float*)d_in[2];
    float* out = (float*)d_out;

    char* ws = (char*)d_ws;
    short* xpad = (short*)ws;                                  // 16,908,288 B
    short* xd   = (short*)(ws + 16908288);                     // 16,908,288 B
    short* Ab   = (short*)(ws + 33816576);                     //  2,097,152 B

    static bool cfgDone = false;
    if (!cfgDone) {
        (void)hipFuncSetAttribute((const void*)stft_gemm_f,
                                  hipFuncAttributeMaxDynamicSharedMemorySize,
                                  69632);
        cfgDone = true;
    }

    prep_x<<<dim3(258, NBC), 256, 0, stream>>>(x, xpad, xd);
    prep_basis2<<<dim3(512, 4), 256, 0, stream>>>(wr, wi, Ab);
    stft_gemm_f<<<dim3(2304), 256, 69632, stream>>>(Ab, xd, out);
    stft_tail<<<dim3(9, NBC), 256, 0, stream>>>(wr, wi, xpad, out);
}